// Round 3
// baseline (578.624 us; speedup 1.0000x reference)
//
#include <hip/hip_runtime.h>
#include <hip/hip_bf16.h>
#include <stdint.h>

// VQ nearest-codebook: B=8,N=4096,C=256,K=8192
// R3: hi-only fp16 GEMM (1/3 MFMA work) + per-subchunk top-2 records +
//     exact-fp32 candidate finalize (margin pruning).
// dist(i,j) = |x|^2 + |c|^2 - 2 x.c ; argmin gap ~10 >> hi-GEMM error (~0.03 std).

#define M_ROWS 32768   // B*N
#define KCODES 8192
#define CDIM   256
#define BM 128
#define BNT 256        // codes per block tile
#define BK 32
#define NSPLIT 4
#define KCHUNK 2048    // codes per chunk (blockIdx.y)
#define NTILES 8       // KCHUNK / BNT
#define KSTEPS 8       // CDIM / BK
#define NREC 32        // subchunk records per row (each covers 256 codes)
#define MARGIN 0.75f   // >> 2*err_bound(~0.32); candidates/row ~= 1.08

typedef _Float16 f16x8 __attribute__((ext_vector_type(8)));
typedef _Float16 f16x4 __attribute__((ext_vector_type(4)));
typedef float    f32x4 __attribute__((ext_vector_type(4)));

// ---------------- prep: fp16 hi (scaled by 64) + row sq-norms ----------------
__global__ void vq_prep(const float* __restrict__ x, const float* __restrict__ cb,
                        _Float16* __restrict__ xhi, _Float16* __restrict__ cbhi,
                        float* __restrict__ xsq, float* __restrict__ cbsq) {
  const int wave = threadIdx.x >> 6, lane = threadIdx.x & 63;
  const int row = blockIdx.x * 4 + wave;     // one wave per row
  const float* src;
  _Float16* dhi;
  float* dsq;
  if (row < M_ROWS) {
    src = x + (size_t)row * CDIM;  dhi = xhi + (size_t)row * CDIM;  dsq = xsq + row;
  } else {
    const int r = row - M_ROWS;
    src = cb + (size_t)r * CDIM;   dhi = cbhi + (size_t)r * CDIM;   dsq = cbsq + r;
  }
  const float4 v = *(const float4*)(src + lane * 4);
  f16x4 h;
  h[0] = (_Float16)(v.x * 64.0f); h[1] = (_Float16)(v.y * 64.0f);
  h[2] = (_Float16)(v.z * 64.0f); h[3] = (_Float16)(v.w * 64.0f);
  *(f16x4*)(dhi + lane * 4) = h;
  float s = v.x * v.x + v.y * v.y + v.z * v.z + v.w * v.w;
  #pragma unroll
  for (int off = 32; off > 0; off >>= 1) s += __shfl_down(s, off, 64);
  if (lane == 0) *dsq = s;
}

// ---------------- pass1: hi GEMM + per-subchunk top-2 records ----------------
__device__ __forceinline__ void gl16(const _Float16* g, _Float16* l) {
  __builtin_amdgcn_global_load_lds(
      (const __attribute__((address_space(1))) unsigned int*)g,
      (__attribute__((address_space(3))) unsigned int*)l, 16, 0, 0);
}

__global__ __launch_bounds__(256, 2) void vq_pass1(
    const _Float16* __restrict__ xhi, const _Float16* __restrict__ cbhi,
    const float* __restrict__ cbsq, float4* __restrict__ srec) {
  const int tid  = threadIdx.x;
  const int wave = tid >> 6, lane = tid & 63;
  const int quad = lane >> 4, l15 = lane & 15;
  const int mbase  = blockIdx.x * BM;
  const int cbase0 = blockIdx.y * KCHUNK;
  const int wrow = (wave >> 1) * 64;         // row half
  const int wcol = (wave & 1) * 128;         // col half

  __shared__ alignas(16) _Float16 sAhi[BM * BK];    //  8 KB
  __shared__ alignas(16) _Float16 sBhi[BNT * BK];   // 16 KB

  // staging: 16B slot XOR-swizzled by (row>>1)&3 (R2: measured 0 conflicts)
  const int srl  = lane >> 2;
  const int scol = (((lane & 3) ^ ((lane >> 3) & 3)) << 3);
  const int fcol = ((quad ^ ((l15 >> 1) & 3)) << 3);

  float v1[4][4], v2[4][4];
  int   i1[4][4], i2[4][4];

  for (int nt = 0; nt < NTILES; ++nt) {
    const int cb0 = cbase0 + nt * BNT;
    if ((nt & 1) == 0) {   // new subchunk (2 nt tiles = 256 codes per col-half)
      #pragma unroll
      for (int mf = 0; mf < 4; ++mf)
        #pragma unroll
        for (int i = 0; i < 4; ++i) {
          v1[mf][i] = __builtin_inff(); v2[mf][i] = __builtin_inff();
          i1[mf][i] = 0; i2[mf][i] = 0;
        }
    }

    f32x4 acc[4][8];
    #pragma unroll
    for (int mf = 0; mf < 4; ++mf)
      #pragma unroll
      for (int nf = 0; nf < 8; ++nf) {
        f32x4 z = {0.0f, 0.0f, 0.0f, 0.0f};
        acc[mf][nf] = z;
      }

    for (int ks = 0; ks < KSTEPS; ++ks) {
      const int kofs = ks * BK;
      __syncthreads();
      #pragma unroll
      for (int t = 0; t < 2; ++t) {
        const int rb = wave * 32 + t * 16;
        gl16(xhi + (mbase + rb + srl) * CDIM + kofs + scol, sAhi + rb * BK);
      }
      #pragma unroll
      for (int t = 0; t < 4; ++t) {
        const int rb = wave * 64 + t * 16;
        gl16(cbhi + (cb0 + rb + srl) * CDIM + kofs + scol, sBhi + rb * BK);
      }
      __syncthreads();

      f16x8 ah[4];
      #pragma unroll
      for (int mf = 0; mf < 4; ++mf)
        ah[mf] = *(const f16x8*)(sAhi + (wrow + mf * 16 + l15) * BK + fcol);
      #pragma unroll
      for (int nf = 0; nf < 8; ++nf) {
        const f16x8 bh = *(const f16x8*)(sBhi + (wcol + nf * 16 + l15) * BK + fcol);
        #pragma unroll
        for (int mf = 0; mf < 4; ++mf)
          acc[mf][nf] = __builtin_amdgcn_mfma_f32_16x16x32_f16(ah[mf], bh, acc[mf][nf], 0, 0, 0);
      }
    }

    // merge this nt tile into subchunk top-2 (value = cbsq - 2*dot; xsq added later)
    #pragma unroll
    for (int nf = 0; nf < 8; ++nf) {
      const int col = cb0 + wcol + nf * 16 + l15;
      const float cq = cbsq[col];
      #pragma unroll
      for (int mf = 0; mf < 4; ++mf)
        #pragma unroll
        for (int i = 0; i < 4; ++i) {
          const float v = fmaf(-0.00048828125f, acc[mf][nf][i], cq);
          if (v < v1[mf][i]) {
            v2[mf][i] = v1[mf][i]; i2[mf][i] = i1[mf][i];
            v1[mf][i] = v;         i1[mf][i] = col;
          } else if (v < v2[mf][i]) {
            v2[mf][i] = v; i2[mf][i] = col;
          }
        }
    }

    if (nt & 1) {   // close subchunk: reduce 16 lanes sharing a row, store record
      const int g = blockIdx.y * 8 + (nt >> 1) * 2 + (wave & 1);  // record id 0..31
      #pragma unroll
      for (int mf = 0; mf < 4; ++mf)
        #pragma unroll
        for (int i = 0; i < 4; ++i) {
          float a1 = v1[mf][i], a2 = v2[mf][i];
          int   b1 = i1[mf][i], b2 = i2[mf][i];
          #pragma unroll
          for (int m = 1; m <= 8; m <<= 1) {
            const float o1 = __shfl_xor(a1, m, 64); const int p1 = __shfl_xor(b1, m, 64);
            const float o2 = __shfl_xor(a2, m, 64); const int p2 = __shfl_xor(b2, m, 64);
            if (o1 < a1 || (o1 == a1 && p1 < b1)) {
              if (a1 < o2 || (a1 == o2 && b1 < p2)) { a2 = a1; b2 = b1; }
              else                                  { a2 = o2; b2 = p2; }
              a1 = o1; b1 = p1;
            } else {
              if (o1 < a2 || (o1 == a2 && p1 < b2)) { a2 = o1; b2 = p1; }
            }
          }
          if (l15 == 0) {
            const int rl = wrow + mf * 16 + quad * 4 + i;   // C/D row
            float4 r;
            r.x = a1; r.y = __int_as_float(b1);
            r.z = a2; r.w = __int_as_float(b2);
            srec[(size_t)(mbase + rl) * NREC + g] = r;
          }
        }
    }
  }
}

// ---------------- finalize: exact fp32 dots for margin candidates ----------------
__global__ void vq_finalize(const float* __restrict__ x, const float* __restrict__ cb,
                            const float* __restrict__ xsq, const float* __restrict__ cbsq,
                            const float4* __restrict__ srec,
                            float* __restrict__ outIdx, float* __restrict__ outDist,
                            float* __restrict__ codes) {
  const int wave = threadIdx.x >> 6, lane = threadIdx.x & 63;
  const int row = blockIdx.x * 4 + wave;    // one wave per row
  float4 rec;
  if (lane < NREC) rec = srec[(size_t)row * NREC + lane];
  else { rec.x = __builtin_inff(); rec.y = 0.0f; rec.z = __builtin_inff(); rec.w = 0.0f; }

  float gm = rec.x;
  #pragma unroll
  for (int m = 1; m <= 32; m <<= 1) gm = fminf(gm, __shfl_xor(gm, m, 64));
  const float thr = gm + MARGIN;
  unsigned long long mask1 = __ballot(rec.x <= thr);
  unsigned long long mask2 = __ballot(rec.z <= thr);

  const float4 xv = *(const float4*)(x + (size_t)row * CDIM + lane * 4);
  const float xq = xsq[row];
  float best = __builtin_inff(); int bidx = 1 << 30;

  #pragma unroll
  for (int pass = 0; pass < 2; ++pass) {
    unsigned long long m = pass ? mask2 : mask1;
    while (m) {
      const int g = __builtin_ctzll((long long)m); m &= m - 1;
      const float fi = pass ? rec.w : rec.y;
      const int ci = __float_as_int(__shfl(fi, g, 64));
      const float4 cv = *(const float4*)(cb + (size_t)ci * CDIM + lane * 4);
      float s = xv.x * cv.x + xv.y * cv.y + xv.z * cv.z + xv.w * cv.w;
      #pragma unroll
      for (int mm = 1; mm <= 32; mm <<= 1) s += __shfl_xor(s, mm, 64);
      const float dist = xq + cbsq[ci] - 2.0f * s;
      if (dist < best || (dist == best && ci < bidx)) { best = dist; bidx = ci; }
    }
  }

  if (lane == 0) { outIdx[row] = (float)bidx; outDist[row] = best; }
  const float4 cw = *(const float4*)(cb + (size_t)bidx * CDIM + lane * 4);
  *(float4*)(codes + (size_t)row * CDIM + lane * 4) = cw;
}

extern "C" void kernel_launch(void* const* d_in, const int* in_sizes, int n_in,
                              void* d_out, int out_size, void* d_ws, size_t ws_size,
                              hipStream_t stream) {
  const float* x  = (const float*)d_in[0];   // [8,4096,256] fp32
  const float* cb = (const float*)d_in[1];   // [8192,256] fp32
  float* out = (float*)d_out;                // codes | idx | dist

  char* w = (char*)d_ws;                     // ~37.9 MB
  _Float16* xhi  = (_Float16*)(w);                 // 16 MB
  _Float16* cbhi = (_Float16*)(w + 16777216);      //  4 MB
  float*    xsq  = (float*)   (w + 20971520);      // 128 KB
  float*    cbsq = (float*)   (w + 21102592);      //  32 KB
  float4*   srec = (float4*)  (w + 21135360);      // 16 MB (32768*32*16B)

  vq_prep<<<(M_ROWS + KCODES) / 4, 256, 0, stream>>>(x, cb, xhi, cbhi, xsq, cbsq);
  vq_pass1<<<dim3(M_ROWS / BM, NSPLIT), 256, 0, stream>>>(xhi, cbhi, cbsq, srec);
  vq_finalize<<<M_ROWS / 4, 256, 0, stream>>>(x, cb, xsq, cbsq, srec,
                                              out + 8388608, out + 8421376, out);
}

// Round 4
// 377.451 us; speedup vs baseline: 1.5330x; 1.5330x over previous
//
#include <hip/hip_runtime.h>
#include <hip/hip_bf16.h>
#include <stdint.h>

// VQ nearest-codebook: B=8,N=4096,C=256,K=8192
// R4: hi-only fp16 GEMM (1/3 MFMA) + per-256-code top-2 records + exact fp32 finalize.
// R3 spilled (acc128+state64 > 256 regs, WRITE_SIZE 297MB). Fix: 64x64 wave tile
// (acc 64 AGPR) + branchless inserts. Algorithm itself verified exact in R3 (absmax=0).

#define M_ROWS 32768   // B*N
#define KCODES 8192
#define CDIM   256
#define BM 128
#define BNT 128        // codes per block tile
#define BK 32
#define NSPLIT 4
#define KCHUNK 2048    // codes per chunk (blockIdx.y)
#define NTILES 16      // KCHUNK / BNT
#define KSTEPS 8       // CDIM / BK
#define NREC 32        // records per row, each covers 256 codes
#define MARGIN 0.75f   // >> 2*hi-GEMM err bound (~0.32)

typedef _Float16 f16x8 __attribute__((ext_vector_type(8)));
typedef _Float16 f16x4 __attribute__((ext_vector_type(4)));
typedef float    f32x4 __attribute__((ext_vector_type(4)));

// ---------------- prep: fp16 hi (scaled by 64) + row sq-norms ----------------
__global__ void vq_prep(const float* __restrict__ x, const float* __restrict__ cb,
                        _Float16* __restrict__ xhi, _Float16* __restrict__ cbhi,
                        float* __restrict__ xsq, float* __restrict__ cbsq) {
  const int wave = threadIdx.x >> 6, lane = threadIdx.x & 63;
  const int row = blockIdx.x * 4 + wave;     // one wave per row
  const float* src;
  _Float16* dhi;
  float* dsq;
  if (row < M_ROWS) {
    src = x + (size_t)row * CDIM;  dhi = xhi + (size_t)row * CDIM;  dsq = xsq + row;
  } else {
    const int r = row - M_ROWS;
    src = cb + (size_t)r * CDIM;   dhi = cbhi + (size_t)r * CDIM;   dsq = cbsq + r;
  }
  const float4 v = *(const float4*)(src + lane * 4);
  f16x4 h;
  h[0] = (_Float16)(v.x * 64.0f); h[1] = (_Float16)(v.y * 64.0f);
  h[2] = (_Float16)(v.z * 64.0f); h[3] = (_Float16)(v.w * 64.0f);
  *(f16x4*)(dhi + lane * 4) = h;
  float s = v.x * v.x + v.y * v.y + v.z * v.z + v.w * v.w;
  #pragma unroll
  for (int off = 32; off > 0; off >>= 1) s += __shfl_down(s, off, 64);
  if (lane == 0) *dsq = s;
}

// ---------------- pass1: hi GEMM + per-subchunk top-2 records ----------------
__device__ __forceinline__ void gl16(const _Float16* g, _Float16* l) {
  __builtin_amdgcn_global_load_lds(
      (const __attribute__((address_space(1))) unsigned int*)g,
      (__attribute__((address_space(3))) unsigned int*)l, 16, 0, 0);
}

__global__ __launch_bounds__(256, 2) void vq_pass1(
    const _Float16* __restrict__ xhi, const _Float16* __restrict__ cbhi,
    const float* __restrict__ cbsq, float4* __restrict__ srec) {
  const int tid  = threadIdx.x;
  const int wave = tid >> 6, lane = tid & 63;
  const int quad = lane >> 4, l15 = lane & 15;
  const int mbase  = blockIdx.x * BM;
  const int cbase0 = blockIdx.y * KCHUNK;
  const int wrow = (wave >> 1) * 64;   // row half
  const int wcol = (wave & 1) * 64;    // col half

  __shared__ alignas(16) _Float16 sAhi[BM * BK];    // 8 KB
  __shared__ alignas(16) _Float16 sBhi[BNT * BK];   // 8 KB

  // XOR swizzle (R2: measured 0 bank conflicts)
  const int srl  = lane >> 2;
  const int scol = (((lane & 3) ^ ((lane >> 3) & 3)) << 3);
  const int fcol = ((quad ^ ((l15 >> 1) & 3)) << 3);

  float v1[4][4], v2[4][4];
  int   i1[4][4], i2[4][4];

  for (int nt = 0; nt < NTILES; ++nt) {
    const int cb0 = cbase0 + nt * BNT;
    if ((nt & 3) == 0) {   // open subchunk (4 tiles x 64 wave-cols = 256 codes)
      #pragma unroll
      for (int mf = 0; mf < 4; ++mf)
        #pragma unroll
        for (int i = 0; i < 4; ++i) {
          v1[mf][i] = __builtin_inff(); v2[mf][i] = __builtin_inff();
          i1[mf][i] = 0; i2[mf][i] = 0;
        }
    }

    f32x4 acc[4][4];
    #pragma unroll
    for (int mf = 0; mf < 4; ++mf)
      #pragma unroll
      for (int nf = 0; nf < 4; ++nf) {
        f32x4 z = {0.0f, 0.0f, 0.0f, 0.0f};
        acc[mf][nf] = z;
      }

    for (int ks = 0; ks < KSTEPS; ++ks) {
      const int kofs = ks * BK;
      __syncthreads();
      #pragma unroll
      for (int t = 0; t < 2; ++t) {
        const int rb = wave * 32 + t * 16;
        gl16(xhi  + (mbase + rb + srl) * CDIM + kofs + scol, sAhi + rb * BK);
        gl16(cbhi + (cb0   + rb + srl) * CDIM + kofs + scol, sBhi + rb * BK);
      }
      __syncthreads();

      f16x8 ah[4], bh[4];
      #pragma unroll
      for (int mf = 0; mf < 4; ++mf)
        ah[mf] = *(const f16x8*)(sAhi + (wrow + mf * 16 + l15) * BK + fcol);
      #pragma unroll
      for (int nf = 0; nf < 4; ++nf)
        bh[nf] = *(const f16x8*)(sBhi + (wcol + nf * 16 + l15) * BK + fcol);
      #pragma unroll
      for (int nf = 0; nf < 4; ++nf)
        #pragma unroll
        for (int mf = 0; mf < 4; ++mf)
          acc[mf][nf] = __builtin_amdgcn_mfma_f32_16x16x32_f16(ah[mf], bh[nf], acc[mf][nf], 0, 0, 0);
    }

    // branchless top-2 insert (cols ascending; strict < keeps lowest idx on tie)
    #pragma unroll
    for (int nf = 0; nf < 4; ++nf) {
      const int col = cb0 + wcol + nf * 16 + l15;   // C/D: col = lane&15
      const float cq = cbsq[col];
      #pragma unroll
      for (int mf = 0; mf < 4; ++mf)
        #pragma unroll
        for (int i = 0; i < 4; ++i) {
          const float v = fmaf(-0.00048828125f, acc[mf][nf][i], cq);
          const bool lt1 = v < v1[mf][i];
          const bool lt2 = v < v2[mf][i];
          v2[mf][i] = lt1 ? v1[mf][i] : (lt2 ? v : v2[mf][i]);
          i2[mf][i] = lt1 ? i1[mf][i] : (lt2 ? col : i2[mf][i]);
          v1[mf][i] = lt1 ? v : v1[mf][i];
          i1[mf][i] = lt1 ? col : i1[mf][i];
        }
    }

    if ((nt & 3) == 3) {   // close subchunk: 16-lane sorted-pair merge, store record
      const int g = blockIdx.y * 8 + (nt >> 2) * 2 + (wave & 1);  // 0..31
      #pragma unroll
      for (int mf = 0; mf < 4; ++mf)
        #pragma unroll
        for (int i = 0; i < 4; ++i) {
          float a1 = v1[mf][i], a2 = v2[mf][i];
          int   b1 = i1[mf][i], b2 = i2[mf][i];
          #pragma unroll
          for (int m = 1; m <= 8; m <<= 1) {
            const float o1 = __shfl_xor(a1, m, 64); const int p1 = __shfl_xor(b1, m, 64);
            const float o2 = __shfl_xor(a2, m, 64); const int p2 = __shfl_xor(b2, m, 64);
            // first = min(a1,o1); second = min(max(a1,o1), min(a2,o2)); idx tie -> lower
            const bool lt  = (o1 < a1) || (o1 == a1 && p1 < b1);
            const float fv = lt ? o1 : a1;  const int fi = lt ? p1 : b1;
            const float sv = lt ? a1 : o1;  const int si = lt ? b1 : p1;
            const bool lt2 = (o2 < a2) || (o2 == a2 && p2 < b2);
            const float mv = lt2 ? o2 : a2; const int mi = lt2 ? p2 : b2;
            const bool lt3 = (mv < sv) || (mv == sv && mi < si);
            a1 = fv; b1 = fi;
            a2 = lt3 ? mv : sv; b2 = lt3 ? mi : si;
          }
          if (l15 == 0) {
            const int rl = wrow + mf * 16 + quad * 4 + i;   // C/D row
            float4 r;
            r.x = a1; r.y = __int_as_float(b1);
            r.z = a2; r.w = __int_as_float(b2);
            srec[(size_t)(mbase + rl) * NREC + g] = r;
          }
        }
    }
  }
}

// ---------------- finalize: exact fp32 dots for margin candidates ----------------
__global__ void vq_finalize(const float* __restrict__ x, const float* __restrict__ cb,
                            const float* __restrict__ xsq, const float* __restrict__ cbsq,
                            const float4* __restrict__ srec,
                            float* __restrict__ outIdx, float* __restrict__ outDist,
                            float* __restrict__ codes) {
  const int wave = threadIdx.x >> 6, lane = threadIdx.x & 63;
  const int row = blockIdx.x * 4 + wave;    // one wave per row
  float4 rec;
  if (lane < NREC) rec = srec[(size_t)row * NREC + lane];
  else { rec.x = __builtin_inff(); rec.y = 0.0f; rec.z = __builtin_inff(); rec.w = 0.0f; }

  float gm = rec.x;
  #pragma unroll
  for (int m = 1; m <= 32; m <<= 1) gm = fminf(gm, __shfl_xor(gm, m, 64));
  const float thr = gm + MARGIN;
  unsigned long long mask1 = __ballot(rec.x <= thr);
  unsigned long long mask2 = __ballot(rec.z <= thr);

  const float4 xv = *(const float4*)(x + (size_t)row * CDIM + lane * 4);
  const float xq = xsq[row];
  float best = __builtin_inff(); int bidx = 1 << 30;

  #pragma unroll
  for (int pass = 0; pass < 2; ++pass) {
    unsigned long long m = pass ? mask2 : mask1;
    while (m) {
      const int g = __builtin_ctzll((long long)m); m &= m - 1;
      const float fi = pass ? rec.w : rec.y;
      const int ci = __float_as_int(__shfl(fi, g, 64));
      const float4 cv = *(const float4*)(cb + (size_t)ci * CDIM + lane * 4);
      float s = xv.x * cv.x + xv.y * cv.y + xv.z * cv.z + xv.w * cv.w;
      #pragma unroll
      for (int mm = 1; mm <= 32; mm <<= 1) s += __shfl_xor(s, mm, 64);
      const float dist = xq + cbsq[ci] - 2.0f * s;
      if (dist < best || (dist == best && ci < bidx)) { best = dist; bidx = ci; }
    }
  }

  if (lane == 0) { outIdx[row] = (float)bidx; outDist[row] = best; }
  const float4 cw = *(const float4*)(cb + (size_t)bidx * CDIM + lane * 4);
  *(float4*)(codes + (size_t)row * CDIM + lane * 4) = cw;
}

extern "C" void kernel_launch(void* const* d_in, const int* in_sizes, int n_in,
                              void* d_out, int out_size, void* d_ws, size_t ws_size,
                              hipStream_t stream) {
  const float* x  = (const float*)d_in[0];   // [8,4096,256] fp32
  const float* cb = (const float*)d_in[1];   // [8192,256] fp32
  float* out = (float*)d_out;                // codes | idx | dist

  char* w = (char*)d_ws;                     // ~37.9 MB
  _Float16* xhi  = (_Float16*)(w);                 // 16 MB
  _Float16* cbhi = (_Float16*)(w + 16777216);      //  4 MB
  float*    xsq  = (float*)   (w + 20971520);      // 128 KB
  float*    cbsq = (float*)   (w + 21102592);      //  32 KB
  float4*   srec = (float4*)  (w + 21135360);      // 16 MB (32768*32*16B)

  vq_prep<<<(M_ROWS + KCODES) / 4, 256, 0, stream>>>(x, cb, xhi, cbhi, xsq, cbsq);
  vq_pass1<<<dim3(M_ROWS / BM, NSPLIT), 256, 0, stream>>>(xhi, cbhi, cbsq, srec);
  vq_finalize<<<M_ROWS / 4, 256, 0, stream>>>(x, cb, xsq, cbsq, srec,
                                              out + 8388608, out + 8421376, out);
}